// Round 1
// baseline (434.896 us; speedup 1.0000x reference)
//
#include <hip/hip_runtime.h>

// CoverageMechanism: out[b,s,v] = logits[b,s,v] - 0.3 * (# occurrences of v
// in tokens[b, s-4 : s]), penalty only for s >= 4.
//
// Shapes (fixed by setup_inputs): B=4, S=512, V=32000.
// Memory-bound: 262 MB read + 262 MB write => ~83 us floor at 6.3 TB/s.
// Strategy: one block per (b,s) row; stream the row as float4 copy with an
// inline 4-token compare fixup. Window tokens are block-uniform -> scalar
// loads, L1-cached (token array is only ~8 KB).

#define VOCAB_SIZE 32000
#define MAX_REPEAT 4
#define PENALTY_W 0.3f
#define SEQ_LEN 512

__global__ __launch_bounds__(256) void coverage_kernel(
    const float* __restrict__ logits,
    const int* __restrict__ tokens,   // harness delivers integer inputs as int32
    float* __restrict__ out)
{
    const int row = blockIdx.x;            // row = b*S + s
    const int s = row & (SEQ_LEN - 1);     // S = 512 (power of two)

    // Window tokens (block-uniform). s < MAX_REPEAT => no penalty (t = -1
    // never matches a vocab index).
    int t0 = -1, t1 = -1, t2 = -1, t3 = -1;
    if (s >= MAX_REPEAT) {
        const int* tp = tokens + row - MAX_REPEAT;  // tokens[b*S + s - 4 ..]
        t0 = tp[0];
        t1 = tp[1];
        t2 = tp[2];
        t3 = tp[3];
    }

    const float4* __restrict__ in4 =
        (const float4*)(logits + (long long)row * VOCAB_SIZE);
    float4* __restrict__ out4 =
        (float4*)(out + (long long)row * VOCAB_SIZE);

    const int n4 = VOCAB_SIZE / 4;  // 8000 float4 per row
    for (int i = threadIdx.x; i < n4; i += 256) {
        float4 x = in4[i];
        const int v = i * 4;
        x.x -= PENALTY_W * (float)((v     == t0) + (v     == t1) + (v     == t2) + (v     == t3));
        x.y -= PENALTY_W * (float)((v + 1 == t0) + (v + 1 == t1) + (v + 1 == t2) + (v + 1 == t3));
        x.z -= PENALTY_W * (float)((v + 2 == t0) + (v + 2 == t1) + (v + 2 == t2) + (v + 2 == t3));
        x.w -= PENALTY_W * (float)((v + 3 == t0) + (v + 3 == t1) + (v + 3 == t2) + (v + 3 == t3));
        out4[i] = x;
    }
}

extern "C" void kernel_launch(void* const* d_in, const int* in_sizes, int n_in,
                              void* d_out, int out_size, void* d_ws, size_t ws_size,
                              hipStream_t stream) {
    const float* logits = (const float*)d_in[0];
    const int* tokens = (const int*)d_in[1];
    float* out = (float*)d_out;

    const int rows = in_sizes[1];  // B * S = 2048
    coverage_kernel<<<rows, 256, 0, stream>>>(logits, tokens, out);
}